// Round 7
// baseline (191.559 us; speedup 1.0000x reference)
//
#include <hip/hip_runtime.h>
#include <hip/hip_bf16.h>
#include <math.h>

#define NS 4096          // samples per view
#define NI 8192          // total instances (2 views)
#define DIM 512          // feature dim (= 512 bytes per row in fp8)
#define TEMP_INV 2.0f    // 1/t, t = 0.5
#define NBLK 128         // NI/64 tile stripes
#define NTRI (NBLK * (NBLK + 1) / 2)   // 8256 upper-triangle 64x64 tiles

typedef int   v8i __attribute__((ext_vector_type(8)));   // 32 fp8 (8 VGPRs)
typedef float v4f __attribute__((ext_vector_type(4)));   // 4 fp32 acc

// ---------------------------------------------------------------------------
// Kernel 1: norms + positive dots (fp32), cast X -> fp8 e4m3.
// ---------------------------------------------------------------------------
__global__ __launch_bounds__(256) void prep_kernel(
        const float* __restrict__ x1, const float* __restrict__ x2,
        unsigned char* __restrict__ Xq, float* __restrict__ rnorm,
        float* __restrict__ posdot) {
    const int t = threadIdx.x;
    const int sub = t >> 7;
    const int c4 = t & 127;
    const int i = blockIdx.x * 2 + sub;
    const float4 a = ((const float4*)(x1 + (size_t)i * DIM))[c4];
    const float4 b = ((const float4*)(x2 + (size_t)i * DIM))[c4];
    float s1 = a.x*a.x + a.y*a.y + a.z*a.z + a.w*a.w;
    float s2 = b.x*b.x + b.y*b.y + b.z*b.z + b.w*b.w;
    float dd = a.x*b.x + a.y*b.y + a.z*b.z + a.w*b.w;

    // pack 4 floats -> 4 e4m3 bytes (RNE)
    int pa = __builtin_amdgcn_cvt_pk_fp8_f32(a.x, a.y, 0, false);
    pa     = __builtin_amdgcn_cvt_pk_fp8_f32(a.z, a.w, pa, true);
    int pb = __builtin_amdgcn_cvt_pk_fp8_f32(b.x, b.y, 0, false);
    pb     = __builtin_amdgcn_cvt_pk_fp8_f32(b.z, b.w, pb, true);
    ((int*)(Xq + (size_t)i * DIM))[c4] = pa;
    ((int*)(Xq + (size_t)(i + NS) * DIM))[c4] = pb;

    #pragma unroll
    for (int off = 32; off; off >>= 1) {
        s1 += __shfl_down(s1, off, 64);
        s2 += __shfl_down(s2, off, 64);
        dd += __shfl_down(dd, off, 64);
    }
    __shared__ float red[2][2][3];
    if ((t & 63) == 0) {
        const int w = (t >> 6) & 1;
        red[sub][w][0] = s1; red[sub][w][1] = s2; red[sub][w][2] = dd;
    }
    __syncthreads();
    if ((t & 127) == 0) {
        s1 = red[sub][0][0] + red[sub][1][0];
        s2 = red[sub][0][1] + red[sub][1][1];
        dd = red[sub][0][2] + red[sub][1][2];
        rnorm[i]      = 1.0f / sqrtf(s1);
        rnorm[i + NS] = 1.0f / sqrtf(s2);
        posdot[i] = dd;
    }
}

// ---------------------------------------------------------------------------
// Kernel 2: ONE WAVE per 64x64 upper-triangle tile of G = Xq*Xq^T via
// mfma_scale_f32_16x16x128_f8f6f4 (unit scales). NO LDS, NO barriers:
// fragments load directly global->VGPR (each staged byte is used exactly
// once per wave, so LDS staging adds no reuse — only latency coupling).
// Compiler emits fine-grained vmcnt waits; ~12+ independent waves/CU
// hide each other. Row/col exp-sums go to collision-free slices
// P[other_stripe][row] (plain stores, exactly one writer per slot).
// ---------------------------------------------------------------------------
__global__ __launch_bounds__(64) void sim_kernel(
        const unsigned char* __restrict__ Xq, const float* __restrict__ rnorm,
        float* __restrict__ P, float* __restrict__ negpart) {
    // --- triangular decode: id -> (bi, bj), bi<=bj, NBLK=128
    const int id = blockIdx.x;
    int bi = (int)((257.0f - sqrtf(66049.0f - 8.0f * (float)id)) * 0.5f);
    int base = bi * (257 - bi) / 2;
    if (id < base)                      { --bi; base = bi * (257 - bi) / 2; }
    else if (id >= base + (NBLK - bi))  { ++bi; base = bi * (257 - bi) / 2; }
    const int bj = bi + (id - base);
    const bool offdiag = (bj != bi);
    const int i0 = bi * 64, j0 = bj * 64;

    const int t = threadIdx.x;          // 64 threads = 1 wave
    const int r16 = t & 15, quad = t >> 4;

    // fragment base addresses: lane (r16,quad) holds A[m=r16][k=quad*32..+31]
    const unsigned char* aBase[4];
    const unsigned char* bBase[4];
    #pragma unroll
    for (int tt = 0; tt < 4; ++tt) {
        aBase[tt] = Xq + (size_t)(i0 + tt * 16 + r16) * DIM + quad * 32;
        bBase[tt] = Xq + (size_t)(j0 + tt * 16 + r16) * DIM + quad * 32;
    }

    v4f acc[4][4];
    #pragma unroll
    for (int a = 0; a < 4; ++a)
        #pragma unroll
        for (int b = 0; b < 4; ++b)
            acc[a][b] = (v4f){0.f, 0.f, 0.f, 0.f};

    const int usc = 0x7F7F7F7F;         // unit e8m0 scales (opsel-immune)

    #pragma unroll
    for (int s = 0; s < DIM / 128; ++s) {   // 4 K-steps of 128
        v8i bf[4];
        #pragma unroll
        for (int tt = 0; tt < 4; ++tt)
            bf[tt] = *(const v8i*)(bBase[tt] + s * 128);
        #pragma unroll
        for (int ta = 0; ta < 4; ++ta) {
            const v8i af = *(const v8i*)(aBase[ta] + s * 128);
            #pragma unroll
            for (int tb = 0; tb < 4; ++tb)
                acc[ta][tb] = __builtin_amdgcn_mfma_scale_f32_16x16x128_f8f6f4(
                    af, bf[tb], acc[ta][tb], 0, 0, 0, usc, 0, usc);
        }
    }

    // --- epilogue: sim2 = 2*D*r_i*r_j; masked (j==i, j==i^NS) -> exp gives 1
    float rc[4];
    int colg[4];
    #pragma unroll
    for (int tb = 0; tb < 4; ++tb) {
        colg[tb] = j0 + tb * 16 + r16;
        rc[tb] = rnorm[colg[tb]];
    }
    float negacc = 0.f;
    float colacc[4] = {0.f, 0.f, 0.f, 0.f};
    #pragma unroll
    for (int ta = 0; ta < 4; ++ta) {
        #pragma unroll
        for (int r = 0; r < 4; ++r) {
            const int rowg = i0 + ta * 16 + quad * 4 + r;
            const float rr = rnorm[rowg] * TEMP_INV;
            float rowe = 0.f;
            #pragma unroll
            for (int tb = 0; tb < 4; ++tb) {
                const float sim2 = acc[ta][tb][r] * rr * rc[tb];
                const bool masked = (colg[tb] == rowg) || (colg[tb] == (rowg ^ NS));
                const float e = masked ? 1.0f : __expf(sim2);
                rowe   += e;
                negacc += masked ? 0.0f : sim2;
                colacc[tb] += e;
            }
            #pragma unroll
            for (int off = 1; off < 16; off <<= 1)
                rowe += __shfl_xor(rowe, off, 64);
            // row-partial for stripe bi, slice bj: exactly one writer
            if (r16 == 0) P[(size_t)bj * NI + rowg] = rowe;
        }
    }
    #pragma unroll
    for (int tb = 0; tb < 4; ++tb) {
        colacc[tb] += __shfl_xor(colacc[tb], 16, 64);
        colacc[tb] += __shfl_xor(colacc[tb], 32, 64);
        // col-partial for stripe bj, slice bi (offdiag only): one writer
        if (offdiag && quad == 0) P[(size_t)bi * NI + colg[tb]] = colacc[tb];
    }
    if (offdiag) negacc *= 2.0f;
    #pragma unroll
    for (int off = 1; off < 64; off <<= 1)
        negacc += __shfl_xor(negacc, off, 64);
    if (t == 0) negpart[id] = negacc;
}

// ---------------------------------------------------------------------------
// Kernel 3: per-row reduction of P + per-row loss terms + negpart slice sums.
// 32 blocks x 256 threads, thread <-> row. Writes partial[blk][3].
// ---------------------------------------------------------------------------
__global__ __launch_bounds__(256) void reduce_kernel(
        const float* __restrict__ P, const float* __restrict__ rnorm,
        const float* __restrict__ posdot, const float* __restrict__ negpart,
        float* __restrict__ partial) {
    const int t = threadIdx.x;
    const int r = blockIdx.x * 256 + t;
    float E = 0.f;
    #pragma unroll 16
    for (int s = 0; s < NBLK; ++s)
        E += P[(size_t)s * NI + r];     // coalesced: consecutive r per s
    const float sp = posdot[r & (NS - 1)] * rnorm[r] * rnorm[r ^ NS] * TEMP_INV;
    float lsum = logf(expf(sp) + E) - sp;
    float psum = sp;
    float nsum = 0.f;
    for (int i = blockIdx.x * 256 + t; i < NTRI; i += 32 * 256)
        nsum += negpart[i];

    __shared__ float red[3][4];
    #pragma unroll
    for (int off = 32; off; off >>= 1) {
        lsum += __shfl_down(lsum, off, 64);
        psum += __shfl_down(psum, off, 64);
        nsum += __shfl_down(nsum, off, 64);
    }
    if ((t & 63) == 0) {
        red[0][t >> 6] = lsum; red[1][t >> 6] = psum; red[2][t >> 6] = nsum;
    }
    __syncthreads();
    if (t == 0) {
        lsum = red[0][0] + red[0][1] + red[0][2] + red[0][3];
        psum = red[1][0] + red[1][1] + red[1][2] + red[1][3];
        nsum = red[2][0] + red[2][1] + red[2][2] + red[2][3];
        partial[blockIdx.x * 3 + 0] = lsum;
        partial[blockIdx.x * 3 + 1] = psum;
        partial[blockIdx.x * 3 + 2] = nsum;
    }
}

// ---------------------------------------------------------------------------
// Kernel 4: final 3 scalars from 32 block partials.
// ---------------------------------------------------------------------------
__global__ __launch_bounds__(64) void final_kernel(
        const float* __restrict__ partial, float* __restrict__ out) {
    const int t = threadIdx.x;
    float l = 0.f, p = 0.f, n = 0.f;
    if (t < 32) {
        l = partial[t * 3 + 0];
        p = partial[t * 3 + 1];
        n = partial[t * 3 + 2];
    }
    #pragma unroll
    for (int off = 1; off < 32; off <<= 1) {
        l += __shfl_xor(l, off, 64);
        p += __shfl_xor(p, off, 64);
        n += __shfl_xor(n, off, 64);
    }
    if (t == 0) {
        out[0] = l / (float)NI;
        out[1] = p / (float)NI;
        out[2] = n / ((float)NI * (float)(NI - 2));
    }
}

// ---------------------------------------------------------------------------
extern "C" void kernel_launch(void* const* d_in, const int* in_sizes, int n_in,
                              void* d_out, int out_size, void* d_ws, size_t ws_size,
                              hipStream_t stream) {
    const float* x1 = (const float*)d_in[0];
    const float* x2 = (const float*)d_in[1];
    float* out = (float*)d_out;

    char* ws = (char*)d_ws;
    unsigned char* Xq = (unsigned char*)ws;                   // NI*DIM = 4 MB
    float* P       = (float*)(ws + (size_t)NI * DIM);         // 128*8192*4 = 4 MB
    float* rnorm   = (float*)(ws + 2 * (size_t)NI * DIM);     // NI
    float* posdot  = rnorm + NI;                              // NS
    float* negpart = posdot + NS;                             // NTRI
    float* partial = negpart + NTRI;                          // 96
    // total = 8 MB + 82.2 KB  (< proven-available 8.47 MB from R4)
    // No zeroing needed: every P slot, negpart entry, partial entry is written.

    prep_kernel<<<NS / 2, 256, 0, stream>>>(x1, x2, Xq, rnorm, posdot);

    sim_kernel<<<NTRI, 64, 0, stream>>>(Xq, rnorm, P, negpart);

    reduce_kernel<<<32, 256, 0, stream>>>(P, rnorm, posdot, negpart, partial);

    final_kernel<<<1, 64, 0, stream>>>(partial, out);
}

// Round 8
// 148.006 us; speedup vs baseline: 1.2943x; 1.2943x over previous
//
#include <hip/hip_runtime.h>
#include <hip/hip_bf16.h>
#include <math.h>

#define NS 4096          // samples per view
#define NI 8192          // total instances (2 views)
#define DIM 512          // feature dim (= 512 bytes per row in fp8)
#define TEMP_INV 2.0f    // 1/t, t = 0.5
#define NBLK 128         // NI/64 stripes
#define NTRI (NBLK * (NBLK + 1) / 2)   // 8256 upper-triangle 64x64 tiles

typedef int   v4i __attribute__((ext_vector_type(4)));
typedef int   v8i __attribute__((ext_vector_type(8)));   // 32 fp8 (8 VGPRs)
typedef float v4f __attribute__((ext_vector_type(4)));   // 4 fp32 acc

// Swizzled fragment layout: for (stripe p, k-stage s, frag tt) a 2 KB block
//   base = ((p*4 + s)*4 + tt) * 2048
// holding 64 rows x 128 k-bytes as (half h, lane, 16B): lane = r16 + 16*kq
// owns row r16 (of rows tt*16..tt*16+15), k-bytes kq*32+h*16+[0,16).
// => sim's fragment load is two fully-coalesced 1 KB dwordx4 transactions.

// ---------------------------------------------------------------------------
// Kernel 1: norms + positive dots (fp32), cast X -> fp8 e4m3 into Xsw.
// ---------------------------------------------------------------------------
__global__ __launch_bounds__(256) void prep_kernel(
        const float* __restrict__ x1, const float* __restrict__ x2,
        unsigned char* __restrict__ Xsw, float* __restrict__ rnorm,
        float* __restrict__ posdot) {
    const int t = threadIdx.x;
    const int sub = t >> 7;
    const int c4 = t & 127;              // float4 index within the row
    const int i = blockIdx.x * 2 + sub;
    const float4 a = ((const float4*)(x1 + (size_t)i * DIM))[c4];
    const float4 b = ((const float4*)(x2 + (size_t)i * DIM))[c4];
    float s1 = a.x*a.x + a.y*a.y + a.z*a.z + a.w*a.w;
    float s2 = b.x*b.x + b.y*b.y + b.z*b.z + b.w*b.w;
    float dd = a.x*b.x + a.y*b.y + a.z*b.z + a.w*b.w;

    int pa = __builtin_amdgcn_cvt_pk_fp8_f32(a.x, a.y, 0, false);
    pa     = __builtin_amdgcn_cvt_pk_fp8_f32(a.z, a.w, pa, true);
    int pb = __builtin_amdgcn_cvt_pk_fp8_f32(b.x, b.y, 0, false);
    pb     = __builtin_amdgcn_cvt_pk_fp8_f32(b.z, b.w, pb, true);

    // dest address pieces from c4 (kb = c4*4)
    const int s   = c4 >> 5;             // k-stage (128 B each)
    const int kq  = (c4 >> 3) & 3;       // 32B quad within stage
    const int h   = (c4 >> 2) & 1;       // 16B half within quad
    const int b16 = (c4 & 3) * 4;        // byte within 16B granule
    auto dst = [&](int row) -> int* {
        const int p = row >> 6, tt = (row >> 4) & 3, r16 = row & 15;
        return (int*)(Xsw + (size_t)(((p * 4 + s) * 4 + tt) * 2048)
                          + (h * 64 + r16 + 16 * kq) * 16 + b16);
    };
    *dst(i) = pa;
    *dst(i + NS) = pb;

    #pragma unroll
    for (int off = 32; off; off >>= 1) {
        s1 += __shfl_down(s1, off, 64);
        s2 += __shfl_down(s2, off, 64);
        dd += __shfl_down(dd, off, 64);
    }
    __shared__ float red[2][2][3];
    if ((t & 63) == 0) {
        const int w = (t >> 6) & 1;
        red[sub][w][0] = s1; red[sub][w][1] = s2; red[sub][w][2] = dd;
    }
    __syncthreads();
    if ((t & 127) == 0) {
        s1 = red[sub][0][0] + red[sub][1][0];
        s2 = red[sub][0][1] + red[sub][1][1];
        dd = red[sub][0][2] + red[sub][1][2];
        rnorm[i]      = 1.0f / sqrtf(s1);
        rnorm[i + NS] = 1.0f / sqrtf(s2);
        posdot[i] = dd;
    }
}

// ---------------------------------------------------------------------------
// Kernel 2: one wave per 64x64 upper-triangle tile; 4 independent waves per
// 256-thread block (tile = 4*bid + wave). NO LDS, NO barriers. Fragments
// load straight from the pre-swizzled Xsw with perfectly coalesced
// dwordx4 pairs. Waves in a block share the A-stripe (consecutive tile ids
// share bi) -> L1 reuse. Epilogue: collision-free P-slice stores (R7).
// ---------------------------------------------------------------------------
__global__ __launch_bounds__(256) void sim_kernel(
        const unsigned char* __restrict__ Xsw, const float* __restrict__ rnorm,
        float* __restrict__ P, float* __restrict__ negpart) {
    const int t = threadIdx.x;
    const int lane = t & 63;
    const int id = blockIdx.x * 4 + (t >> 6);       // 0..8255 exactly

    // --- triangular decode: id -> (bi, bj), bi<=bj, NBLK=128
    int bi = (int)((257.0f - sqrtf(66049.0f - 8.0f * (float)id)) * 0.5f);
    int base = bi * (257 - bi) / 2;
    if (id < base)                      { --bi; base = bi * (257 - bi) / 2; }
    else if (id >= base + (NBLK - bi))  { ++bi; base = bi * (257 - bi) / 2; }
    const int bj = bi + (id - base);
    const bool offdiag = (bj != bi);
    const int i0 = bi * 64, j0 = bj * 64;
    const int r16 = lane & 15, quad = lane >> 4;

    // fragment bases: A-stripe bi, B-stripe bj; frag (s,tt) at +s*8192+tt*2048
    const unsigned char* aS = Xsw + (size_t)bi * 4 * 8192 + (size_t)lane * 16;
    const unsigned char* bS = Xsw + (size_t)bj * 4 * 8192 + (size_t)lane * 16;

    v4f acc[4][4];
    #pragma unroll
    for (int a = 0; a < 4; ++a)
        #pragma unroll
        for (int b = 0; b < 4; ++b)
            acc[a][b] = (v4f){0.f, 0.f, 0.f, 0.f};

    const int usc = 0x7F7F7F7F;         // unit e8m0 scales (opsel-immune)

    #pragma unroll
    for (int s = 0; s < 4; ++s) {       // 4 K-steps of 128
        v8i bf[4];
        #pragma unroll
        for (int tt = 0; tt < 4; ++tt) {
            const unsigned char* fb = bS + s * 8192 + tt * 2048;
            const v4i lo = *(const v4i*)(fb);
            const v4i hi = *(const v4i*)(fb + 1024);
            bf[tt] = __builtin_shufflevector(lo, hi, 0, 1, 2, 3, 4, 5, 6, 7);
        }
        #pragma unroll
        for (int ta = 0; ta < 4; ++ta) {
            const unsigned char* fa = aS + s * 8192 + ta * 2048;
            const v4i lo = *(const v4i*)(fa);
            const v4i hi = *(const v4i*)(fa + 1024);
            const v8i af = __builtin_shufflevector(lo, hi, 0, 1, 2, 3, 4, 5, 6, 7);
            #pragma unroll
            for (int tb = 0; tb < 4; ++tb)
                acc[ta][tb] = __builtin_amdgcn_mfma_scale_f32_16x16x128_f8f6f4(
                    af, bf[tb], acc[ta][tb], 0, 0, 0, usc, 0, usc);
        }
    }

    // --- epilogue: sim2 = 2*D*r_i*r_j; masked (j==i, j==i^NS) -> exp gives 1
    float rc[4];
    int colg[4];
    #pragma unroll
    for (int tb = 0; tb < 4; ++tb) {
        colg[tb] = j0 + tb * 16 + r16;
        rc[tb] = rnorm[colg[tb]];
    }
    float negacc = 0.f;
    float colacc[4] = {0.f, 0.f, 0.f, 0.f};
    #pragma unroll
    for (int ta = 0; ta < 4; ++ta) {
        #pragma unroll
        for (int r = 0; r < 4; ++r) {
            const int rowg = i0 + ta * 16 + quad * 4 + r;
            const float rr = rnorm[rowg] * TEMP_INV;
            float rowe = 0.f;
            #pragma unroll
            for (int tb = 0; tb < 4; ++tb) {
                const float sim2 = acc[ta][tb][r] * rr * rc[tb];
                const bool masked = (colg[tb] == rowg) || (colg[tb] == (rowg ^ NS));
                const float e = masked ? 1.0f : __expf(sim2);
                rowe   += e;
                negacc += masked ? 0.0f : sim2;
                colacc[tb] += e;
            }
            #pragma unroll
            for (int off = 1; off < 16; off <<= 1)
                rowe += __shfl_xor(rowe, off, 64);
            if (r16 == 0) P[(size_t)bj * NI + rowg] = rowe;   // one writer/slot
        }
    }
    #pragma unroll
    for (int tb = 0; tb < 4; ++tb) {
        colacc[tb] += __shfl_xor(colacc[tb], 16, 64);
        colacc[tb] += __shfl_xor(colacc[tb], 32, 64);
        if (offdiag && quad == 0) P[(size_t)bi * NI + colg[tb]] = colacc[tb];
    }
    if (offdiag) negacc *= 2.0f;
    #pragma unroll
    for (int off = 1; off < 64; off <<= 1)
        negacc += __shfl_xor(negacc, off, 64);
    if (lane == 0) negpart[id] = negacc;
}

// ---------------------------------------------------------------------------
// Kernel 3: per-row reduction of P + per-row loss terms + negpart sums.
// ---------------------------------------------------------------------------
__global__ __launch_bounds__(256) void reduce_kernel(
        const float* __restrict__ P, const float* __restrict__ rnorm,
        const float* __restrict__ posdot, const float* __restrict__ negpart,
        float* __restrict__ partial) {
    const int t = threadIdx.x;
    const int r = blockIdx.x * 256 + t;
    float E = 0.f;
    #pragma unroll 16
    for (int s = 0; s < NBLK; ++s)
        E += P[(size_t)s * NI + r];     // coalesced: consecutive r per s
    const float sp = posdot[r & (NS - 1)] * rnorm[r] * rnorm[r ^ NS] * TEMP_INV;
    float lsum = logf(expf(sp) + E) - sp;
    float psum = sp;
    float nsum = 0.f;
    for (int i = blockIdx.x * 256 + t; i < NTRI; i += 32 * 256)
        nsum += negpart[i];

    __shared__ float red[3][4];
    #pragma unroll
    for (int off = 32; off; off >>= 1) {
        lsum += __shfl_down(lsum, off, 64);
        psum += __shfl_down(psum, off, 64);
        nsum += __shfl_down(nsum, off, 64);
    }
    if ((t & 63) == 0) {
        red[0][t >> 6] = lsum; red[1][t >> 6] = psum; red[2][t >> 6] = nsum;
    }
    __syncthreads();
    if (t == 0) {
        lsum = red[0][0] + red[0][1] + red[0][2] + red[0][3];
        psum = red[1][0] + red[1][1] + red[1][2] + red[1][3];
        nsum = red[2][0] + red[2][1] + red[2][2] + red[2][3];
        partial[blockIdx.x * 3 + 0] = lsum;
        partial[blockIdx.x * 3 + 1] = psum;
        partial[blockIdx.x * 3 + 2] = nsum;
    }
}

// ---------------------------------------------------------------------------
// Kernel 4: final 3 scalars from 32 block partials.
// ---------------------------------------------------------------------------
__global__ __launch_bounds__(64) void final_kernel(
        const float* __restrict__ partial, float* __restrict__ out) {
    const int t = threadIdx.x;
    float l = 0.f, p = 0.f, n = 0.f;
    if (t < 32) {
        l = partial[t * 3 + 0];
        p = partial[t * 3 + 1];
        n = partial[t * 3 + 2];
    }
    #pragma unroll
    for (int off = 1; off < 32; off <<= 1) {
        l += __shfl_xor(l, off, 64);
        p += __shfl_xor(p, off, 64);
        n += __shfl_xor(n, off, 64);
    }
    if (t == 0) {
        out[0] = l / (float)NI;
        out[1] = p / (float)NI;
        out[2] = n / ((float)NI * (float)(NI - 2));
    }
}

// ---------------------------------------------------------------------------
extern "C" void kernel_launch(void* const* d_in, const int* in_sizes, int n_in,
                              void* d_out, int out_size, void* d_ws, size_t ws_size,
                              hipStream_t stream) {
    const float* x1 = (const float*)d_in[0];
    const float* x2 = (const float*)d_in[1];
    float* out = (float*)d_out;

    char* ws = (char*)d_ws;
    unsigned char* Xsw = (unsigned char*)ws;                  // NI*DIM = 4 MB
    float* P       = (float*)(ws + (size_t)NI * DIM);         // 128*8192*4 = 4 MB
    float* rnorm   = (float*)(ws + 2 * (size_t)NI * DIM);     // NI
    float* posdot  = rnorm + NI;                              // NS
    float* negpart = posdot + NS;                             // NTRI
    float* partial = negpart + NTRI;                          // 96
    // No zeroing needed: every P slot / negpart / partial entry is written.

    prep_kernel<<<NS / 2, 256, 0, stream>>>(x1, x2, Xsw, rnorm, posdot);

    sim_kernel<<<NTRI / 4, 256, 0, stream>>>(Xsw, rnorm, P, negpart);

    reduce_kernel<<<32, 256, 0, stream>>>(P, rnorm, posdot, negpart, partial);

    final_kernel<<<1, 64, 0, stream>>>(partial, out);
}